// Round 2
// baseline (6665.648 us; speedup 1.0000x reference)
//
#include <hip/hip_runtime.h>
#include <hip/hip_bf16.h>
#include <cstdint>
#include <cmath>
#include <vector>
#include <algorithm>
#include <numeric>

// ---------------------------------------------------------------------------
// LapSWD loss: Laplacian pyramid (5 levels) -> 128 random 7x7x3 patches/level
// -> per-channel normalize -> project onto 512 random dirs -> sort columns ->
// mean |sorted1 - sorted2| -> mean over levels * 1000.
// jax.random replicated with threefry2x32 using the PARTITIONABLE (foldlike)
// split/random_bits (jax_threefry_partitionable=True, default in modern JAX):
//   split(key)[i]          = cipher(key, (0, i))       (both outputs = key i)
//   random_bits(key,32)[i] = out0 ^ out1 of cipher(key, (0, i))
// fold_in(key, d)          = cipher(key, (0, d))       (unchanged by the flag)
// ---------------------------------------------------------------------------

__constant__ float KW[5] = {0.0625f, 0.25f, 0.375f, 0.25f, 0.0625f};

struct RC { unsigned int rc[128]; };  // (row<<16)|col per descriptor

// ---- threefry2x32 block cipher, exact JAX/XLA schedule ----
__host__ __device__ inline void tf2x32(uint32_t k0, uint32_t k1,
                                       uint32_t x0, uint32_t x1,
                                       uint32_t& o0, uint32_t& o1) {
  uint32_t k2 = k0 ^ k1 ^ 0x1BD11BDAu;
  x0 += k0; x1 += k1;
#define TFR(r) { x0 += x1; x1 = (x1 << r) | (x1 >> (32 - r)); x1 ^= x0; }
  TFR(13) TFR(15) TFR(26) TFR(6)   x0 += k1; x1 += k2 + 1u;
  TFR(17) TFR(29) TFR(16) TFR(24)  x0 += k2; x1 += k0 + 2u;
  TFR(13) TFR(15) TFR(26) TFR(6)   x0 += k0; x1 += k1 + 3u;
  TFR(17) TFR(29) TFR(16) TFR(24)  x0 += k1; x1 += k2 + 4u;
  TFR(13) TFR(15) TFR(26) TFR(6)   x0 += k2; x1 += k0 + 5u;
#undef TFR
  o0 = x0; o1 = x1;
}

__device__ inline float erfinv_f(float x) {
  // XLA ErfInv32: w = -log1p(-x*x)
  float w = -log1pf(-x * x);
  float p;
  if (w < 5.0f) {
    w = w - 2.5f;
    p = 2.81022636e-08f;
    p = fmaf(p, w, 3.43273939e-07f);
    p = fmaf(p, w, -3.5233877e-06f);
    p = fmaf(p, w, -4.39150654e-06f);
    p = fmaf(p, w, 0.00021858087f);
    p = fmaf(p, w, -0.00125372503f);
    p = fmaf(p, w, -0.00417768164f);
    p = fmaf(p, w, 0.246640727f);
    p = fmaf(p, w, 1.50140941f);
  } else {
    w = sqrtf(w) - 3.0f;
    p = -0.000200214257f;
    p = fmaf(p, w, 0.000100950558f);
    p = fmaf(p, w, 0.00134934322f);
    p = fmaf(p, w, -0.00367342844f);
    p = fmaf(p, w, 0.00573950773f);
    p = fmaf(p, w, -0.0076224613f);
    p = fmaf(p, w, 0.00943887047f);
    p = fmaf(p, w, 1.00167406f);
    p = fmaf(p, w, 2.83297682f);
  }
  return p * x;
}

__device__ inline float bits_to_normal(uint32_t b) {
  // JAX uniform(lo=nextafter(-1,0), hi=1): f = bitcast((b>>9)|0x3f800000)-1
  // u = max(lo, f*(hi-lo) + lo); n = sqrt(2)*erfinv(u)
  union { uint32_t u; float f; } cv;
  cv.u = (b >> 9) | 0x3f800000u;
  float f = cv.f - 1.0f;
  const float lo = -0.99999994f;
  const float span = 1.0f - lo;  // == 2.0f in f32
  float u = fmaxf(lo, __fadd_rn(__fmul_rn(f, span), lo));
  return 1.41421356237f * erfinv_f(u);
}

// ---- kernels ----

__global__ void init_kernel(float* m) {
  int i = threadIdx.x;
  if (i < 128) m[i] = 0.f;
}

__global__ __launch_bounds__(256) void down_kernel(
    const float* __restrict__ in, float* __restrict__ out,
    int H, int W, int total) {
  int idx = blockIdx.x * 256 + threadIdx.x;
  if (idx >= total) return;
  int Wo = W >> 1, Ho = H >> 1;
  int ox = idx % Wo;
  int t = idx / Wo;
  int oy = t % Ho;
  int bc = t / Ho;
  const float* src = in + (size_t)bc * H * W;
  float s = 0.f;
#pragma unroll
  for (int u = 0; u < 5; ++u) {
    int y = 2 * oy + u - 2;
    if (y < 0 || y >= H) continue;
    const float* r = src + (size_t)y * W;
#pragma unroll
    for (int v = 0; v < 5; ++v) {
      int x = 2 * ox + v - 2;
      if (x < 0 || x >= W) continue;
      s += KW[u] * KW[v] * r[x];
    }
  }
  out[idx] = s;
}

__global__ void randgen_kernel(float* __restrict__ rnd, uint32_t k0, uint32_t k1) {
  int t = blockIdx.x * 256 + threadIdx.x;  // grid covers 81920 = 160*512
  const int total = 75264;                 // 147*512
  if (t < total) {
    uint32_t o0, o1;
    tf2x32(k0, k1, 0u, (uint32_t)t, o0, o1);
    rnd[t] = bits_to_normal(o0 ^ o1);
  } else if (t < 81920) {
    rnd[t] = 0.f;  // K padding rows 147..159
  }
}

__global__ void randnorm_kernel(float* __restrict__ rnd) {
  int j = blockIdx.x * 256 + threadIdx.x;  // 512 columns
  if (j >= 512) return;
  float sum = 0.f;
  for (int f = 0; f < 147; ++f) sum += rnd[f * 512 + j];
  float mean = sum * (1.f / 147.f);
  float q = 0.f;
  for (int f = 0; f < 147; ++f) {
    float d = rnd[f * 512 + j] - mean;
    q += d * d;
  }
  float inv = 1.f / sqrtf(q * (1.f / 146.f));  // ddof=1
  for (int f = 0; f < 147; ++f) rnd[f * 512 + j] *= inv;
}

__global__ __launch_bounds__(256) void extract_kernel(
    const float* __restrict__ g, const float* __restrict__ gn,
    float* __restrict__ p, RC rcs, int H, int W, int nd, int useLap, int total) {
  int idx = blockIdx.x * 256 + threadIdx.x;
  if (idx >= total) return;             // total = 128*nd*160
  int col = idx % 160;
  int row = idx / 160;
  if (col >= 147) { p[idx] = 0.f; return; }
  int d = row % nd, b = row / nd;
  int c = col / 49, uv = col % 49, u = uv / 7, v = uv % 7;
  unsigned rc = rcs.rc[d];
  int y = (int)(rc >> 16) + u;
  int x = (int)(rc & 0xffffu) + v;
  const float* gc = g + ((size_t)(b * 3 + c)) * H * W;
  float val = gc[(size_t)y * W + x];
  if (useLap) {
    int H2 = H >> 1, W2 = W >> 1;
    const float* gnc = gn + ((size_t)(b * 3 + c)) * H2 * W2;
    float s = 0.f;
#pragma unroll
    for (int a = -2; a <= 2; ++a) {
      int yy = y + a;
      if (yy < 0 || yy >= H) continue;
      const float* rowp = gnc + (size_t)(yy >> 1) * W2;
#pragma unroll
      for (int bb = -2; bb <= 2; ++bb) {
        int xx = x + bb;
        if (xx < 0 || xx >= W) continue;
        s += KW[a + 2] * KW[bb + 2] * rowp[xx >> 1];
      }
    }
    val -= s;
  }
  p[idx] = val;
}

__global__ __launch_bounds__(256) void stats_kernel(
    const float* __restrict__ p, float* __restrict__ st, int M) {
  __shared__ float ls[6];
  if (threadIdx.x < 6) ls[threadIdx.x] = 0.f;
  __syncthreads();
  int idx = blockIdx.x * 256 + threadIdx.x;
  int total = M * 147;
  if (idx < total) {
    int col = idx % 147;
    int row = idx / 147;
    float v = p[(size_t)row * 160 + col];
    int c = col / 49;
    atomicAdd(&ls[c], v);
    atomicAdd(&ls[3 + c], v * v);
  }
  __syncthreads();
  if (threadIdx.x < 6) atomicAdd(&st[threadIdx.x], ls[threadIdx.x]);
}

__global__ __launch_bounds__(256) void norm_kernel(
    float* __restrict__ p, const float* __restrict__ st, int M) {
  int idx = blockIdx.x * 256 + threadIdx.x;
  int total = M * 147;
  if (idx >= total) return;
  int col = idx % 147;
  int row = idx / 147;
  int c = col / 49;
  float N = (float)M * 49.f;
  float mean = st[c] / N;
  float var = (st[3 + c] - N * mean * mean) / (N - 1.f);
  float sd = sqrtf(fmaxf(var, 0.f));
  size_t o = (size_t)row * 160 + col;
  p[o] = (p[o] - mean) / (sd + 1e-8f);
}

// C[n][m] column-major (stride 16384) = A[M][160] * B[160][512]
#define BM 64
#define BN 64
#define BK 16
__global__ __launch_bounds__(256) void gemm_kernel(
    const float* __restrict__ A, const float* __restrict__ B,
    float* __restrict__ C, int M) {
  __shared__ __align__(16) float As[BK][BM + 4];
  __shared__ __align__(16) float Bs[BK][BN];
  int bm = blockIdx.x * BM;
  int bn = blockIdx.y * BN;
  int tid = threadIdx.x;
  int tm = tid % 16;  // 4 consecutive m per thread
  int tn = tid / 16;  // 4 consecutive n per thread
  float acc[4][4] = {{0.f}};
  for (int k0 = 0; k0 < 160; k0 += BK) {
    for (int t = tid; t < BM * BK; t += 256) {
      int r = t / BK, c = t % BK;
      As[c][r] = A[(size_t)(bm + r) * 160 + k0 + c];
    }
    for (int t = tid; t < BK * BN; t += 256) {
      int r = t / BN, c = t % BN;
      Bs[r][c] = B[(size_t)(k0 + r) * 512 + bn + c];
    }
    __syncthreads();
#pragma unroll
    for (int kk = 0; kk < BK; ++kk) {
      float4 a = *(const float4*)(&As[kk][tm * 4]);
      float4 b = *(const float4*)(&Bs[kk][tn * 4]);
      float av[4] = {a.x, a.y, a.z, a.w};
      float bv[4] = {b.x, b.y, b.z, b.w};
#pragma unroll
      for (int i = 0; i < 4; ++i)
#pragma unroll
        for (int j = 0; j < 4; ++j) acc[i][j] = fmaf(av[i], bv[j], acc[i][j]);
    }
    __syncthreads();
  }
#pragma unroll
  for (int j = 0; j < 4; ++j) {
    int n = bn + tn * 4 + j;
    float4 v = make_float4(acc[0][j], acc[1][j], acc[2][j], acc[3][j]);
    *(float4*)(&C[(size_t)n * 16384 + bm + tm * 4]) = v;
  }
}

__global__ __launch_bounds__(1024) void sort_kernel(
    float* __restrict__ proj1, float* __restrict__ proj2, int m) {
  __shared__ float s[16384];
  int col = blockIdx.x;  // 0..1023
  float* basep = ((col < 512) ? proj1 : proj2) + (size_t)(col & 511) * 16384;
  const float INF = __builtin_huge_valf();
  for (int i = threadIdx.x; i < 16384; i += 1024)
    s[i] = (i < m) ? basep[i] : INF;
  __syncthreads();
  for (int k = 2; k <= 16384; k <<= 1) {
    for (int j = k >> 1; j > 0; j >>= 1) {
#pragma unroll 1
      for (int t = threadIdx.x; t < 8192; t += 1024) {
        int low = t & (j - 1);
        int i = ((t - low) << 1) | low;
        int pi = i | j;
        float a = s[i], b = s[pi];
        float lo = fminf(a, b), hi = fmaxf(a, b);
        bool up = ((i & k) == 0);
        s[i] = up ? lo : hi;
        s[pi] = up ? hi : lo;
      }
      __syncthreads();
    }
  }
  for (int i = threadIdx.x; i < m; i += 1024) basep[i] = s[i];
}

__global__ __launch_bounds__(256) void diff_kernel(
    const float* __restrict__ s1, const float* __restrict__ s2,
    float* __restrict__ sum, int m) {
  int r = blockIdx.x * 256 + threadIdx.x;  // r < m by grid construction
  size_t off = (size_t)blockIdx.y * 16384 + r;
  float v = fabsf(s1[off] - s2[off]);
#pragma unroll
  for (int o = 32; o > 0; o >>= 1) v += __shfl_down(v, o, 64);
  __shared__ float ws_[4];
  if ((threadIdx.x & 63) == 0) ws_[threadIdx.x >> 6] = v;
  __syncthreads();
  if (threadIdx.x == 0) atomicAdd(sum, ws_[0] + ws_[1] + ws_[2] + ws_[3]);
}

__global__ void final_kernel(const float* __restrict__ sums, float* __restrict__ out) {
  float r = sums[0] * (1.f / 8388608.f) + sums[1] * (1.f / 8388608.f) +
            sums[2] * (1.f / 8388608.f) + sums[3] * (1.f / 8388608.f) +
            sums[4] * (1.f / 6553600.f);
  out[0] = r * (1000.f / 5.f);
}

// ---------------------------------------------------------------------------

extern "C" void kernel_launch(void* const* d_in, const int* in_sizes, int n_in,
                              void* d_out, int out_size, void* d_ws, size_t ws_size,
                              hipStream_t stream) {
  const float* xin = (const float*)d_in[0];
  const float* yin = (const float*)d_in[1];
  float* out = (float*)d_out;

  char* base = (char*)d_ws;
  size_t off = 0;
  auto alloc = [&](size_t nfloats) -> float* {
    float* p = (float*)(base + off);
    off += ((nfloats * 4) + 255) & ~(size_t)255;
    return p;
  };
  float* gX[5];
  float* gY[5];
  gX[0] = (float*)xin;  // read-only use
  gY[0] = (float*)yin;
  gX[1] = alloc(6291456); gX[2] = alloc(1572864); gX[3] = alloc(393216); gX[4] = alloc(98304);
  gY[1] = alloc(6291456); gY[2] = alloc(1572864); gY[3] = alloc(393216); gY[4] = alloc(98304);
  float* p1 = alloc((size_t)16384 * 160);
  float* p2 = alloc((size_t)16384 * 160);
  float* rnd = alloc(160 * 512);
  float* proj1 = alloc((size_t)16384 * 512);
  float* proj2 = alloc((size_t)16384 * 512);
  float* misc = alloc(128);  // [0..4] level sums; [8+l*16 ...] per-level stats

  // ---- host: exact JAX threefry (partitionable) for patch indices + keys ----
  static const int Hs[5] = {256, 128, 64, 32, 16};
  RC rcs[5];
  uint32_t kp0[5], kp1[5];
  for (int l = 0; l < 5; ++l) {
    uint32_t f0, f1;
    tf2x32(0u, 42u, 0u, (uint32_t)l, f0, f1);  // fold_in(key(42), l)
    // partitionable split: keys[i] = cipher(key, (0, i))
    uint32_t ik0, ik1;
    tf2x32(f0, f1, 0u, 0u, ik0, ik1);          // k_idx = split[0]
    tf2x32(f0, f1, 0u, 1u, kp0[l], kp1[l]);    // k_proj = split[1]
    int Wm6 = Hs[l] - 6;
    int n = Wm6 * Wm6;
    int nd = n < 128 ? n : 128;
    // jax sort-based shuffle (partitionable random_bits: out0^out1 @ (0,i))
    std::vector<int> perm(n);
    std::iota(perm.begin(), perm.end(), 0);
    int rounds = (int)std::ceil(3.0 * std::log((double)n) / std::log(4294967295.0));
    uint32_t key0 = ik0, key1 = ik1;
    std::vector<uint32_t> bits(n);
    std::vector<int> ord(n), tmp(n);
    for (int r = 0; r < rounds; ++r) {
      uint32_t nk0, nk1, s0, s1;
      tf2x32(key0, key1, 0u, 0u, nk0, nk1);  // new key = split[0]
      tf2x32(key0, key1, 0u, 1u, s0, s1);    // subkey  = split[1]
      key0 = nk0; key1 = nk1;
      for (int t = 0; t < n; ++t) {
        uint32_t o0, o1;
        tf2x32(s0, s1, 0u, (uint32_t)t, o0, o1);
        bits[t] = o0 ^ o1;
      }
      std::iota(ord.begin(), ord.end(), 0);
      std::stable_sort(ord.begin(), ord.end(),
                       [&](int A, int B) { return bits[A] < bits[B]; });
      for (int i2 = 0; i2 < n; ++i2) tmp[i2] = perm[ord[i2]];
      perm.swap(tmp);
    }
    for (int d = 0; d < 128; ++d) {
      int v = (d < nd) ? perm[d] : 0;
      rcs[l].rc[d] = ((uint32_t)(v / Wm6) << 16) | (uint32_t)(v % Wm6);
    }
  }

  // ---- device pipeline ----
  init_kernel<<<1, 128, 0, stream>>>(misc);
  for (int t = 0; t < 2; ++t) {
    const float* in0 = t ? yin : xin;
    float** g = t ? gY : gX;
    down_kernel<<<(384 * 128 * 128 + 255) / 256, 256, 0, stream>>>(in0, g[1], 256, 256, 384 * 128 * 128);
    down_kernel<<<(384 * 64 * 64 + 255) / 256, 256, 0, stream>>>(g[1], g[2], 128, 128, 384 * 64 * 64);
    down_kernel<<<(384 * 32 * 32 + 255) / 256, 256, 0, stream>>>(g[2], g[3], 64, 64, 384 * 32 * 32);
    down_kernel<<<(384 * 16 * 16 + 255) / 256, 256, 0, stream>>>(g[3], g[4], 32, 32, 384 * 16 * 16);
  }
  for (int l = 0; l < 5; ++l) {
    int H = Hs[l];
    int Wm6 = H - 6;
    int n = Wm6 * Wm6;
    int nd = n < 128 ? n : 128;
    int M = 128 * nd;
    randgen_kernel<<<320, 256, 0, stream>>>(rnd, kp0[l], kp1[l]);
    randnorm_kernel<<<2, 256, 0, stream>>>(rnd);
    int totalE = M * 160;
    const float* gx = gX[l];
    const float* gnx = (l < 4) ? gX[l + 1] : nullptr;
    const float* gy = gY[l];
    const float* gny = (l < 4) ? gY[l + 1] : nullptr;
    extract_kernel<<<(totalE + 255) / 256, 256, 0, stream>>>(gx, gnx, p1, rcs[l], H, H, nd, (l < 4) ? 1 : 0, totalE);
    extract_kernel<<<(totalE + 255) / 256, 256, 0, stream>>>(gy, gny, p2, rcs[l], H, H, nd, (l < 4) ? 1 : 0, totalE);
    float* st1 = misc + 8 + l * 16;
    float* st2 = st1 + 6;
    int totalS = M * 147;
    stats_kernel<<<(totalS + 255) / 256, 256, 0, stream>>>(p1, st1, M);
    stats_kernel<<<(totalS + 255) / 256, 256, 0, stream>>>(p2, st2, M);
    norm_kernel<<<(totalS + 255) / 256, 256, 0, stream>>>(p1, st1, M);
    norm_kernel<<<(totalS + 255) / 256, 256, 0, stream>>>(p2, st2, M);
    dim3 gg(M / 64, 8);
    gemm_kernel<<<gg, 256, 0, stream>>>(p1, rnd, proj1, M);
    gemm_kernel<<<gg, 256, 0, stream>>>(p2, rnd, proj2, M);
    sort_kernel<<<1024, 1024, 0, stream>>>(proj1, proj2, M);
    diff_kernel<<<dim3(M / 256, 512), 256, 0, stream>>>(proj1, proj2, misc + l, M);
  }
  final_kernel<<<1, 1, 0, stream>>>(misc, out);
}

// Round 4
// 3628.237 us; speedup vs baseline: 1.8372x; 1.8372x over previous
//
#include <hip/hip_runtime.h>
#include <hip/hip_bf16.h>
#include <cstdint>
#include <cmath>
#include <vector>
#include <algorithm>
#include <numeric>

// ---------------------------------------------------------------------------
// LapSWD loss. RNG = exact JAX partitionable threefry (verified absmax 0.0).
// R4: host-side RNG table construction moved to static-init time (it is a
// pure function of constants) — kernel_launch now does the same cheap work
// on every call, fixing the graph-replay tripwire.
// ---------------------------------------------------------------------------

__constant__ float KW[5] = {0.0625f, 0.25f, 0.375f, 0.25f, 0.0625f};

struct RC { unsigned int rc[128]; };

// ---- threefry2x32 block cipher, exact JAX/XLA schedule ----
__host__ __device__ inline void tf2x32(uint32_t k0, uint32_t k1,
                                       uint32_t x0, uint32_t x1,
                                       uint32_t& o0, uint32_t& o1) {
  uint32_t k2 = k0 ^ k1 ^ 0x1BD11BDAu;
  x0 += k0; x1 += k1;
#define TFR(r) { x0 += x1; x1 = (x1 << r) | (x1 >> (32 - r)); x1 ^= x0; }
  TFR(13) TFR(15) TFR(26) TFR(6)   x0 += k1; x1 += k2 + 1u;
  TFR(17) TFR(29) TFR(16) TFR(24)  x0 += k2; x1 += k0 + 2u;
  TFR(13) TFR(15) TFR(26) TFR(6)   x0 += k0; x1 += k1 + 3u;
  TFR(17) TFR(29) TFR(16) TFR(24)  x0 += k1; x1 += k2 + 4u;
  TFR(13) TFR(15) TFR(26) TFR(6)   x0 += k2; x1 += k0 + 5u;
#undef TFR
  o0 = x0; o1 = x1;
}

// ---- host tables (pure constants; computed once at library load) ----
struct HostTables {
  RC rcs[5];
  uint32_t kp0[5], kp1[5];
  HostTables() {
    static const int Hs[5] = {256, 128, 64, 32, 16};
    for (int l = 0; l < 5; ++l) {
      uint32_t f0, f1;
      tf2x32(0u, 42u, 0u, (uint32_t)l, f0, f1);  // fold_in(key(42), l)
      uint32_t ik0, ik1;
      tf2x32(f0, f1, 0u, 0u, ik0, ik1);          // k_idx = split[0]
      tf2x32(f0, f1, 0u, 1u, kp0[l], kp1[l]);    // k_proj = split[1]
      int Wm6 = Hs[l] - 6;
      int n = Wm6 * Wm6;
      int nd = n < 128 ? n : 128;
      std::vector<int> perm(n);
      std::iota(perm.begin(), perm.end(), 0);
      int rounds = (int)std::ceil(3.0 * std::log((double)n) / std::log(4294967295.0));
      uint32_t key0 = ik0, key1 = ik1;
      std::vector<uint32_t> bits(n);
      std::vector<int> ord(n), tmp(n);
      for (int r = 0; r < rounds; ++r) {
        uint32_t nk0, nk1, s0, s1;
        tf2x32(key0, key1, 0u, 0u, nk0, nk1);
        tf2x32(key0, key1, 0u, 1u, s0, s1);
        key0 = nk0; key1 = nk1;
        for (int tt = 0; tt < n; ++tt) {
          uint32_t o0, o1;
          tf2x32(s0, s1, 0u, (uint32_t)tt, o0, o1);
          bits[tt] = o0 ^ o1;
        }
        std::iota(ord.begin(), ord.end(), 0);
        std::stable_sort(ord.begin(), ord.end(),
                         [&](int A, int B) { return bits[A] < bits[B]; });
        for (int i2 = 0; i2 < n; ++i2) tmp[i2] = perm[ord[i2]];
        perm.swap(tmp);
      }
      for (int d = 0; d < 128; ++d) {
        int vv = (d < nd) ? perm[d] : 0;
        rcs[l].rc[d] = ((uint32_t)(vv / Wm6) << 16) | (uint32_t)(vv % Wm6);
      }
    }
  }
};
static const HostTables g_tbl;

__device__ inline float erfinv_f(float x) {
  float w = -log1pf(-x * x);
  float p;
  if (w < 5.0f) {
    w = w - 2.5f;
    p = 2.81022636e-08f;
    p = fmaf(p, w, 3.43273939e-07f);
    p = fmaf(p, w, -3.5233877e-06f);
    p = fmaf(p, w, -4.39150654e-06f);
    p = fmaf(p, w, 0.00021858087f);
    p = fmaf(p, w, -0.00125372503f);
    p = fmaf(p, w, -0.00417768164f);
    p = fmaf(p, w, 0.246640727f);
    p = fmaf(p, w, 1.50140941f);
  } else {
    w = sqrtf(w) - 3.0f;
    p = -0.000200214257f;
    p = fmaf(p, w, 0.000100950558f);
    p = fmaf(p, w, 0.00134934322f);
    p = fmaf(p, w, -0.00367342844f);
    p = fmaf(p, w, 0.00573950773f);
    p = fmaf(p, w, -0.0076224613f);
    p = fmaf(p, w, 0.00943887047f);
    p = fmaf(p, w, 1.00167406f);
    p = fmaf(p, w, 2.83297682f);
  }
  return p * x;
}

__device__ inline float bits_to_normal(uint32_t b) {
  union { uint32_t u; float f; } cv;
  cv.u = (b >> 9) | 0x3f800000u;
  float f = cv.f - 1.0f;
  const float lo = -0.99999994f;
  const float span = 1.0f - lo;
  float u = fmaxf(lo, __fadd_rn(__fmul_rn(f, span), lo));
  return 1.41421356237f * erfinv_f(u);
}

// ---- kernels ----

__global__ void init_kernel(float* m) {
  int i = threadIdx.x;
  if (i < 128) m[i] = 0.f;
}

__global__ __launch_bounds__(256) void down_kernel(
    const float* __restrict__ in, float* __restrict__ out,
    int H, int W, int total) {
  int idx = blockIdx.x * 256 + threadIdx.x;
  if (idx >= total) return;
  int Wo = W >> 1, Ho = H >> 1;
  int ox = idx % Wo;
  int t = idx / Wo;
  int oy = t % Ho;
  int bc = t / Ho;
  const float* src = in + (size_t)bc * H * W;
  float s = 0.f;
#pragma unroll
  for (int u = 0; u < 5; ++u) {
    int y = 2 * oy + u - 2;
    if (y < 0 || y >= H) continue;
    const float* r = src + (size_t)y * W;
#pragma unroll
    for (int v = 0; v < 5; ++v) {
      int x = 2 * ox + v - 2;
      if (x < 0 || x >= W) continue;
      s += KW[u] * KW[v] * r[x];
    }
  }
  out[idx] = s;
}

__global__ void randgen_kernel(float* __restrict__ rnd, uint32_t k0, uint32_t k1) {
  int t = blockIdx.x * 256 + threadIdx.x;  // grid covers 81920
  const int total = 75264;                 // 147*512
  if (t < total) {
    uint32_t o0, o1;
    tf2x32(k0, k1, 0u, (uint32_t)t, o0, o1);
    rnd[t] = bits_to_normal(o0 ^ o1);
  }
}

// extract + per-channel stats (sum, sumsq) fused
__global__ __launch_bounds__(256) void extract_kernel(
    const float* __restrict__ g, const float* __restrict__ gn,
    float* __restrict__ p, float* __restrict__ st, RC rcs,
    int H, int nd, int useLap, int total) {
  __shared__ float ls[6];
  if (threadIdx.x < 6) ls[threadIdx.x] = 0.f;
  __syncthreads();
  int idx = blockIdx.x * 256 + threadIdx.x;
  if (idx < total) {                    // total = M*160
    int col = idx % 160;
    if (col < 147) {
      int row = idx / 160;
      int d = row % nd, b = row / nd;
      int c = col / 49, uv = col % 49, u = uv / 7, v = uv % 7;
      unsigned rc = rcs.rc[d];
      int y = (int)(rc >> 16) + u;
      int x = (int)(rc & 0xffffu) + v;
      const float* gc = g + ((size_t)(b * 3 + c)) * H * H;
      float val = gc[(size_t)y * H + x];
      if (useLap) {
        int H2 = H >> 1;
        const float* gnc = gn + ((size_t)(b * 3 + c)) * H2 * H2;
        int h = y >> 1, w = x >> 1;
        int yo = y & 1, xo = x & 1;
        // nearest-up 2x + 5-tap collapses to parity-dependent 3-tap
        float rw0 = (y >= 2) ? (yo ? 0.0625f : 0.3125f) : 0.f;
        float rw2 = (y <= H - 3) ? (yo ? 0.3125f : 0.0625f) : 0.f;
        float cw0 = (x >= 2) ? (xo ? 0.0625f : 0.3125f) : 0.f;
        float cw2 = (x <= H - 3) ? (xo ? 0.3125f : 0.0625f) : 0.f;
        int r0 = max(h - 1, 0), r2 = min(h + 1, H2 - 1);
        int c0 = max(w - 1, 0), c2 = min(w + 1, H2 - 1);
        const float* R0 = gnc + (size_t)r0 * H2;
        const float* R1 = gnc + (size_t)h * H2;
        const float* R2 = gnc + (size_t)r2 * H2;
        float s0 = cw0 * R0[c0] + 0.625f * R0[w] + cw2 * R0[c2];
        float s1 = cw0 * R1[c0] + 0.625f * R1[w] + cw2 * R1[c2];
        float s2 = cw0 * R2[c0] + 0.625f * R2[w] + cw2 * R2[c2];
        val -= rw0 * s0 + 0.625f * s1 + rw2 * s2;
      }
      p[idx] = val;
      atomicAdd(&ls[c], val);
      atomicAdd(&ls[3 + c], val * val);
    }
  }
  __syncthreads();
  if (threadIdx.x < 6) atomicAdd(&st[threadIdx.x], ls[threadIdx.x]);
}

// Build adjusted projection matrices: B' = rnd/colstd/(sd_c+eps), plus
// bias[j] = sum_f mean_c * B'[f][j].  (p-m)/(s+eps) @ R == p@B' - bias.
__global__ void prep_kernel(const float* __restrict__ rnd,
                            const float* __restrict__ st,   // st1[6], st2 at +6
                            float* __restrict__ B1, float* __restrict__ B2,
                            float* __restrict__ bias, float Np) {
  int j = blockIdx.x * 256 + threadIdx.x;
  if (j >= 512) return;
  float sum = 0.f, q = 0.f;
  for (int f = 0; f < 147; ++f) {
    float v = rnd[f * 512 + j];
    sum += v; q = fmaf(v, v, q);
  }
  float mean = sum * (1.f / 147.f);
  float var = (q - 147.f * mean * mean) * (1.f / 146.f);
  float inv1 = 1.f / sqrtf(var);
  float b1 = 0.f, b2 = 0.f;
#pragma unroll
  for (int c = 0; c < 3; ++c) {
    float m1 = st[c] / Np;
    float v1 = (st[3 + c] - Np * m1 * m1) / (Np - 1.f);
    float i1 = 1.f / (sqrtf(fmaxf(v1, 0.f)) + 1e-8f);
    float m2 = st[6 + c] / Np;
    float v2 = (st[9 + c] - Np * m2 * m2) / (Np - 1.f);
    float i2 = 1.f / (sqrtf(fmaxf(v2, 0.f)) + 1e-8f);
    for (int ff = 0; ff < 49; ++ff) {
      int f = c * 49 + ff;
      float rv = rnd[f * 512 + j] * inv1;
      float w1 = rv * i1; B1[f * 512 + j] = w1; b1 = fmaf(m1, w1, b1);
      float w2 = rv * i2; B2[f * 512 + j] = w2; b2 = fmaf(m2, w2, b2);
    }
  }
  for (int f = 147; f < 160; ++f) { B1[f * 512 + j] = 0.f; B2[f * 512 + j] = 0.f; }
  bias[j] = b1; bias[512 + j] = b2;
}

// C[n][m] col-major (stride 16384) = A[M][160] * B[160][512] - bias[n]
#define GBM 128
#define GBN 128
#define GBK 16
__global__ __launch_bounds__(256) void gemm_kernel(
    const float* __restrict__ A, const float* __restrict__ B,
    const float* __restrict__ bias, float* __restrict__ C, int M) {
  __shared__ __align__(16) float As[GBK][GBM + 4];
  __shared__ __align__(16) float Bs[GBK][GBN];
  int bm = blockIdx.x * GBM;
  int bn = blockIdx.y * GBN;
  int tid = threadIdx.x;
  int tm = tid & 15;   // 8 consecutive m
  int tn = tid >> 4;   // 8 consecutive n
  float acc[8][8] = {{0.f}};
  for (int k0 = 0; k0 < 160; k0 += GBK) {
#pragma unroll
    for (int i = 0; i < 2; ++i) {
      int q = tid + i * 256;            // 512 float4 of A tile
      int r = q >> 2, c4 = (q & 3) << 2;
      float4 va = *(const float4*)(A + (size_t)(bm + r) * 160 + k0 + c4);
      As[c4 + 0][r] = va.x; As[c4 + 1][r] = va.y;
      As[c4 + 2][r] = va.z; As[c4 + 3][r] = va.w;
    }
#pragma unroll
    for (int i = 0; i < 2; ++i) {
      int q = tid + i * 256;            // 512 float4 of B tile
      int r = q >> 5, c = (q & 31) << 2;
      *(float4*)(&Bs[r][c]) = *(const float4*)(B + (size_t)(k0 + r) * 512 + bn + c);
    }
    __syncthreads();
#pragma unroll
    for (int kk = 0; kk < GBK; ++kk) {
      float4 a0 = *(const float4*)(&As[kk][tm * 8]);
      float4 a1 = *(const float4*)(&As[kk][tm * 8 + 4]);
      float4 b0 = *(const float4*)(&Bs[kk][tn * 8]);
      float4 b1 = *(const float4*)(&Bs[kk][tn * 8 + 4]);
      float av[8] = {a0.x, a0.y, a0.z, a0.w, a1.x, a1.y, a1.z, a1.w};
      float bv[8] = {b0.x, b0.y, b0.z, b0.w, b1.x, b1.y, b1.z, b1.w};
#pragma unroll
      for (int i = 0; i < 8; ++i)
#pragma unroll
        for (int jj = 0; jj < 8; ++jj)
          acc[i][jj] = fmaf(av[i], bv[jj], acc[i][jj]);
    }
    __syncthreads();
  }
#pragma unroll
  for (int jj = 0; jj < 8; ++jj) {
    int n = bn + tn * 8 + jj;
    float bb = bias[n];
    float4 v0 = make_float4(acc[0][jj] - bb, acc[1][jj] - bb, acc[2][jj] - bb, acc[3][jj] - bb);
    float4 v1 = make_float4(acc[4][jj] - bb, acc[5][jj] - bb, acc[6][jj] - bb, acc[7][jj] - bb);
    float* cp = C + (size_t)n * 16384 + bm + tm * 8;
    *(float4*)cp = v0;
    *(float4*)(cp + 4) = v1;
  }
}

// ---- fused sort+diff: 1024 threads x 16 elements, register-blocked bitonic
__device__ inline int sw_idx(int t, int r) {
  return (t << 4) + ((r + ((t & 63) >> 1)) & 15);  // 2-way (free) bank access
}

#define REGPASS(J)                                                    \
  {                                                                   \
    _Pragma("unroll")                                                 \
    for (int r = 0; r < 16; ++r) {                                    \
      if ((r & (J)) == 0) {                                           \
        int i = (t << 4) | r;                                         \
        bool up = ((i & k) == 0);                                     \
        float a = v[r], b = v[r | (J)];                               \
        float lo = fminf(a, b), hi = fmaxf(a, b);                     \
        v[r] = up ? lo : hi;                                          \
        v[r | (J)] = up ? hi : lo;                                    \
      }                                                               \
    }                                                                 \
  }

__global__ __launch_bounds__(1024) void sortdiff_kernel(
    const float* __restrict__ proj1, const float* __restrict__ proj2,
    float* __restrict__ sum, int m) {
  __shared__ float s[16384];
  int t = threadIdx.x;
  int col = blockIdx.x;  // 0..511
  const float INF = __builtin_huge_valf();
  float v[16], keep[16];

  for (int phase = 0; phase < 2; ++phase) {
    const float* basep = (phase ? proj2 : proj1) + (size_t)col * 16384;
    if ((t << 4) < m) {
#pragma unroll
      for (int i = 0; i < 4; ++i) {
        float4 L = *(const float4*)(basep + (t << 4) + i * 4);
        v[i * 4 + 0] = L.x; v[i * 4 + 1] = L.y; v[i * 4 + 2] = L.z; v[i * 4 + 3] = L.w;
      }
    } else {
#pragma unroll
      for (int r = 0; r < 16; ++r) v[r] = INF;
    }

    for (int k = 2; k <= 16384; k <<= 1) {
      // LDS passes: j = k/2 .. 1024
      for (int j = k >> 1; j >= 1024; j >>= 1) {
        __syncthreads();
#pragma unroll
        for (int r = 0; r < 16; ++r) s[sw_idx(t, r)] = v[r];
        __syncthreads();
        int d = j >> 4;
        int pt = t ^ d;
        bool keepmin = ((((t << 4) & k) == 0) == ((t & d) == 0));
#pragma unroll
        for (int r = 0; r < 16; ++r) {
          float pv = s[sw_idx(pt, r)];
          float lo = fminf(v[r], pv), hi = fmaxf(v[r], pv);
          v[r] = keepmin ? lo : hi;
        }
      }
      // shuffle passes: j = min(k/2,512) .. 16
      for (int j = ((k >> 1) < 512 ? (k >> 1) : 512); j >= 16; j >>= 1) {
        int d = j >> 4;  // 1..32 lanes
        bool keepmin = ((((t << 4) & k) == 0) == ((t & d) == 0));
#pragma unroll
        for (int r = 0; r < 16; ++r) {
          float pv = __shfl_xor(v[r], d, 64);
          float lo = fminf(v[r], pv), hi = fmaxf(v[r], pv);
          v[r] = keepmin ? lo : hi;
        }
      }
      // register passes: j = 8,4,2,1
      if (k >= 16) REGPASS(8)
      if (k >= 8)  REGPASS(4)
      if (k >= 4)  REGPASS(2)
      REGPASS(1)
    }

    if (phase == 0) {
#pragma unroll
      for (int r = 0; r < 16; ++r) keep[r] = v[r];
    }
  }

  float acc = 0.f;
  if ((t << 4) < m) {
#pragma unroll
    for (int r = 0; r < 16; ++r) acc += fabsf(keep[r] - v[r]);
  }
#pragma unroll
  for (int o = 32; o > 0; o >>= 1) acc += __shfl_down(acc, o, 64);
  __syncthreads();
  if ((t & 63) == 0) s[t >> 6] = acc;
  __syncthreads();
  if (t == 0) {
    float tot = 0.f;
    for (int i = 0; i < 16; ++i) tot += s[i];
    atomicAdd(sum, tot);
  }
}

__global__ void final_kernel(const float* __restrict__ sums, float* __restrict__ out) {
  float r = sums[0] * (1.f / 8388608.f) + sums[1] * (1.f / 8388608.f) +
            sums[2] * (1.f / 8388608.f) + sums[3] * (1.f / 8388608.f) +
            sums[4] * (1.f / 6553600.f);
  out[0] = r * (1000.f / 5.f);
}

// ---------------------------------------------------------------------------

extern "C" void kernel_launch(void* const* d_in, const int* in_sizes, int n_in,
                              void* d_out, int out_size, void* d_ws, size_t ws_size,
                              hipStream_t stream) {
  const float* xin = (const float*)d_in[0];
  const float* yin = (const float*)d_in[1];
  float* out = (float*)d_out;

  char* base = (char*)d_ws;
  size_t off = 0;
  auto alloc = [&](size_t nfloats) -> float* {
    float* p = (float*)(base + off);
    off += ((nfloats * 4) + 255) & ~(size_t)255;
    return p;
  };
  float* gX[5];
  float* gY[5];
  gX[0] = (float*)xin;
  gY[0] = (float*)yin;
  gX[1] = alloc(6291456); gX[2] = alloc(1572864); gX[3] = alloc(393216); gX[4] = alloc(98304);
  gY[1] = alloc(6291456); gY[2] = alloc(1572864); gY[3] = alloc(393216); gY[4] = alloc(98304);
  float* p1 = alloc((size_t)16384 * 160);
  float* p2 = alloc((size_t)16384 * 160);
  float* rnd = alloc(160 * 512);
  float* B1 = alloc(160 * 512);
  float* B2 = alloc(160 * 512);
  float* biasb = alloc(1024);
  float* proj1 = alloc((size_t)16384 * 512);
  float* proj2 = alloc((size_t)16384 * 512);
  float* misc = alloc(128);  // [0..4] level sums; [8+l*16 ..] stats (12/level)

  static const int Hs[5] = {256, 128, 64, 32, 16};

  // ---- device pipeline ----
  init_kernel<<<1, 128, 0, stream>>>(misc);
  for (int t = 0; t < 2; ++t) {
    const float* in0 = t ? yin : xin;
    float** g = t ? gY : gX;
    down_kernel<<<(384 * 128 * 128 + 255) / 256, 256, 0, stream>>>(in0, g[1], 256, 256, 384 * 128 * 128);
    down_kernel<<<(384 * 64 * 64 + 255) / 256, 256, 0, stream>>>(g[1], g[2], 128, 128, 384 * 64 * 64);
    down_kernel<<<(384 * 32 * 32 + 255) / 256, 256, 0, stream>>>(g[2], g[3], 64, 64, 384 * 32 * 32);
    down_kernel<<<(384 * 16 * 16 + 255) / 256, 256, 0, stream>>>(g[3], g[4], 32, 32, 384 * 16 * 16);
  }
  for (int l = 0; l < 5; ++l) {
    int H = Hs[l];
    int Wm6 = H - 6;
    int n = Wm6 * Wm6;
    int nd = n < 128 ? n : 128;
    int M = 128 * nd;
    randgen_kernel<<<320, 256, 0, stream>>>(rnd, g_tbl.kp0[l], g_tbl.kp1[l]);
    int totalE = M * 160;
    float* st1 = misc + 8 + l * 16;
    float* st2 = st1 + 6;
    extract_kernel<<<(totalE + 255) / 256, 256, 0, stream>>>(
        gX[l], (l < 4) ? gX[l + 1] : nullptr, p1, st1, g_tbl.rcs[l], H, nd, (l < 4) ? 1 : 0, totalE);
    extract_kernel<<<(totalE + 255) / 256, 256, 0, stream>>>(
        gY[l], (l < 4) ? gY[l + 1] : nullptr, p2, st2, g_tbl.rcs[l], H, nd, (l < 4) ? 1 : 0, totalE);
    prep_kernel<<<2, 256, 0, stream>>>(rnd, st1, B1, B2, biasb, (float)M * 49.f);
    dim3 gg(M / 128, 4);
    gemm_kernel<<<gg, 256, 0, stream>>>(p1, B1, biasb, proj1, M);
    gemm_kernel<<<gg, 256, 0, stream>>>(p2, B2, biasb + 512, proj2, M);
    sortdiff_kernel<<<512, 1024, 0, stream>>>(proj1, proj2, misc + l, M);
  }
  final_kernel<<<1, 1, 0, stream>>>(misc, out);
}

// Round 5
// 3128.850 us; speedup vs baseline: 2.1304x; 1.1596x over previous
//
#include <hip/hip_runtime.h>
#include <hip/hip_bf16.h>
#include <cstdint>
#include <cmath>
#include <vector>
#include <algorithm>
#include <numeric>

// ---------------------------------------------------------------------------
// LapSWD loss. RNG = exact JAX partitionable threefry (verified absmax 0.0).
// R5: sortdiff rewritten as hybrid sort — per-wave bitonic (k<=1024, register+
// shuffle only, final stage forced ascending) + 4 merge-path rounds
// (L=1024..8192) with in-register bitonic-merge-16. Phase-0 sorted column is
// written back to global to keep VGPR pressure low.
// ---------------------------------------------------------------------------

__constant__ float KW[5] = {0.0625f, 0.25f, 0.375f, 0.25f, 0.0625f};

struct RC { unsigned int rc[128]; };

// ---- threefry2x32 block cipher, exact JAX/XLA schedule ----
__host__ __device__ inline void tf2x32(uint32_t k0, uint32_t k1,
                                       uint32_t x0, uint32_t x1,
                                       uint32_t& o0, uint32_t& o1) {
  uint32_t k2 = k0 ^ k1 ^ 0x1BD11BDAu;
  x0 += k0; x1 += k1;
#define TFR(r) { x0 += x1; x1 = (x1 << r) | (x1 >> (32 - r)); x1 ^= x0; }
  TFR(13) TFR(15) TFR(26) TFR(6)   x0 += k1; x1 += k2 + 1u;
  TFR(17) TFR(29) TFR(16) TFR(24)  x0 += k2; x1 += k0 + 2u;
  TFR(13) TFR(15) TFR(26) TFR(6)   x0 += k0; x1 += k1 + 3u;
  TFR(17) TFR(29) TFR(16) TFR(24)  x0 += k1; x1 += k2 + 4u;
  TFR(13) TFR(15) TFR(26) TFR(6)   x0 += k2; x1 += k0 + 5u;
#undef TFR
  o0 = x0; o1 = x1;
}

// ---- host tables (pure constants; computed once at library load) ----
struct HostTables {
  RC rcs[5];
  uint32_t kp0[5], kp1[5];
  HostTables() {
    static const int Hs[5] = {256, 128, 64, 32, 16};
    for (int l = 0; l < 5; ++l) {
      uint32_t f0, f1;
      tf2x32(0u, 42u, 0u, (uint32_t)l, f0, f1);  // fold_in(key(42), l)
      uint32_t ik0, ik1;
      tf2x32(f0, f1, 0u, 0u, ik0, ik1);          // k_idx = split[0]
      tf2x32(f0, f1, 0u, 1u, kp0[l], kp1[l]);    // k_proj = split[1]
      int Wm6 = Hs[l] - 6;
      int n = Wm6 * Wm6;
      int nd = n < 128 ? n : 128;
      std::vector<int> perm(n);
      std::iota(perm.begin(), perm.end(), 0);
      int rounds = (int)std::ceil(3.0 * std::log((double)n) / std::log(4294967295.0));
      uint32_t key0 = ik0, key1 = ik1;
      std::vector<uint32_t> bits(n);
      std::vector<int> ord(n), tmp(n);
      for (int r = 0; r < rounds; ++r) {
        uint32_t nk0, nk1, s0, s1;
        tf2x32(key0, key1, 0u, 0u, nk0, nk1);
        tf2x32(key0, key1, 0u, 1u, s0, s1);
        key0 = nk0; key1 = nk1;
        for (int tt = 0; tt < n; ++tt) {
          uint32_t o0, o1;
          tf2x32(s0, s1, 0u, (uint32_t)tt, o0, o1);
          bits[tt] = o0 ^ o1;
        }
        std::iota(ord.begin(), ord.end(), 0);
        std::stable_sort(ord.begin(), ord.end(),
                         [&](int A, int B) { return bits[A] < bits[B]; });
        for (int i2 = 0; i2 < n; ++i2) tmp[i2] = perm[ord[i2]];
        perm.swap(tmp);
      }
      for (int d = 0; d < 128; ++d) {
        int vv = (d < nd) ? perm[d] : 0;
        rcs[l].rc[d] = ((uint32_t)(vv / Wm6) << 16) | (uint32_t)(vv % Wm6);
      }
    }
  }
};
static const HostTables g_tbl;

__device__ inline float erfinv_f(float x) {
  float w = -log1pf(-x * x);
  float p;
  if (w < 5.0f) {
    w = w - 2.5f;
    p = 2.81022636e-08f;
    p = fmaf(p, w, 3.43273939e-07f);
    p = fmaf(p, w, -3.5233877e-06f);
    p = fmaf(p, w, -4.39150654e-06f);
    p = fmaf(p, w, 0.00021858087f);
    p = fmaf(p, w, -0.00125372503f);
    p = fmaf(p, w, -0.00417768164f);
    p = fmaf(p, w, 0.246640727f);
    p = fmaf(p, w, 1.50140941f);
  } else {
    w = sqrtf(w) - 3.0f;
    p = -0.000200214257f;
    p = fmaf(p, w, 0.000100950558f);
    p = fmaf(p, w, 0.00134934322f);
    p = fmaf(p, w, -0.00367342844f);
    p = fmaf(p, w, 0.00573950773f);
    p = fmaf(p, w, -0.0076224613f);
    p = fmaf(p, w, 0.00943887047f);
    p = fmaf(p, w, 1.00167406f);
    p = fmaf(p, w, 2.83297682f);
  }
  return p * x;
}

__device__ inline float bits_to_normal(uint32_t b) {
  union { uint32_t u; float f; } cv;
  cv.u = (b >> 9) | 0x3f800000u;
  float f = cv.f - 1.0f;
  const float lo = -0.99999994f;
  const float span = 1.0f - lo;
  float u = fmaxf(lo, __fadd_rn(__fmul_rn(f, span), lo));
  return 1.41421356237f * erfinv_f(u);
}

// ---- kernels ----

__global__ void init_kernel(float* m) {
  int i = threadIdx.x;
  if (i < 128) m[i] = 0.f;
}

__global__ __launch_bounds__(256) void down_kernel(
    const float* __restrict__ in, float* __restrict__ out,
    int H, int W, int total) {
  int idx = blockIdx.x * 256 + threadIdx.x;
  if (idx >= total) return;
  int Wo = W >> 1, Ho = H >> 1;
  int ox = idx % Wo;
  int t = idx / Wo;
  int oy = t % Ho;
  int bc = t / Ho;
  const float* src = in + (size_t)bc * H * W;
  float s = 0.f;
#pragma unroll
  for (int u = 0; u < 5; ++u) {
    int y = 2 * oy + u - 2;
    if (y < 0 || y >= H) continue;
    const float* r = src + (size_t)y * W;
#pragma unroll
    for (int v = 0; v < 5; ++v) {
      int x = 2 * ox + v - 2;
      if (x < 0 || x >= W) continue;
      s += KW[u] * KW[v] * r[x];
    }
  }
  out[idx] = s;
}

__global__ void randgen_kernel(float* __restrict__ rnd, uint32_t k0, uint32_t k1) {
  int t = blockIdx.x * 256 + threadIdx.x;  // grid covers 81920
  const int total = 75264;                 // 147*512
  if (t < total) {
    uint32_t o0, o1;
    tf2x32(k0, k1, 0u, (uint32_t)t, o0, o1);
    rnd[t] = bits_to_normal(o0 ^ o1);
  }
}

// extract + per-channel stats (sum, sumsq) fused
__global__ __launch_bounds__(256) void extract_kernel(
    const float* __restrict__ g, const float* __restrict__ gn,
    float* __restrict__ p, float* __restrict__ st, RC rcs,
    int H, int nd, int useLap, int total) {
  __shared__ float ls[6];
  if (threadIdx.x < 6) ls[threadIdx.x] = 0.f;
  __syncthreads();
  int idx = blockIdx.x * 256 + threadIdx.x;
  if (idx < total) {                    // total = M*160
    int col = idx % 160;
    if (col < 147) {
      int row = idx / 160;
      int d = row % nd, b = row / nd;
      int c = col / 49, uv = col % 49, u = uv / 7, v = uv % 7;
      unsigned rc = rcs.rc[d];
      int y = (int)(rc >> 16) + u;
      int x = (int)(rc & 0xffffu) + v;
      const float* gc = g + ((size_t)(b * 3 + c)) * H * H;
      float val = gc[(size_t)y * H + x];
      if (useLap) {
        int H2 = H >> 1;
        const float* gnc = gn + ((size_t)(b * 3 + c)) * H2 * H2;
        int h = y >> 1, w = x >> 1;
        int yo = y & 1, xo = x & 1;
        float rw0 = (y >= 2) ? (yo ? 0.0625f : 0.3125f) : 0.f;
        float rw2 = (y <= H - 3) ? (yo ? 0.3125f : 0.0625f) : 0.f;
        float cw0 = (x >= 2) ? (xo ? 0.0625f : 0.3125f) : 0.f;
        float cw2 = (x <= H - 3) ? (xo ? 0.3125f : 0.0625f) : 0.f;
        int r0 = max(h - 1, 0), r2 = min(h + 1, H2 - 1);
        int c0 = max(w - 1, 0), c2 = min(w + 1, H2 - 1);
        const float* R0 = gnc + (size_t)r0 * H2;
        const float* R1 = gnc + (size_t)h * H2;
        const float* R2 = gnc + (size_t)r2 * H2;
        float s0 = cw0 * R0[c0] + 0.625f * R0[w] + cw2 * R0[c2];
        float s1 = cw0 * R1[c0] + 0.625f * R1[w] + cw2 * R1[c2];
        float s2 = cw0 * R2[c0] + 0.625f * R2[w] + cw2 * R2[c2];
        val -= rw0 * s0 + 0.625f * s1 + rw2 * s2;
      }
      p[idx] = val;
      atomicAdd(&ls[c], val);
      atomicAdd(&ls[3 + c], val * val);
    }
  }
  __syncthreads();
  if (threadIdx.x < 6) atomicAdd(&st[threadIdx.x], ls[threadIdx.x]);
}

__global__ void prep_kernel(const float* __restrict__ rnd,
                            const float* __restrict__ st,   // st1[6], st2 at +6
                            float* __restrict__ B1, float* __restrict__ B2,
                            float* __restrict__ bias, float Np) {
  int j = blockIdx.x * 256 + threadIdx.x;
  if (j >= 512) return;
  float sum = 0.f, q = 0.f;
  for (int f = 0; f < 147; ++f) {
    float v = rnd[f * 512 + j];
    sum += v; q = fmaf(v, v, q);
  }
  float mean = sum * (1.f / 147.f);
  float var = (q - 147.f * mean * mean) * (1.f / 146.f);
  float inv1 = 1.f / sqrtf(var);
  float b1 = 0.f, b2 = 0.f;
#pragma unroll
  for (int c = 0; c < 3; ++c) {
    float m1 = st[c] / Np;
    float v1 = (st[3 + c] - Np * m1 * m1) / (Np - 1.f);
    float i1 = 1.f / (sqrtf(fmaxf(v1, 0.f)) + 1e-8f);
    float m2 = st[6 + c] / Np;
    float v2 = (st[9 + c] - Np * m2 * m2) / (Np - 1.f);
    float i2 = 1.f / (sqrtf(fmaxf(v2, 0.f)) + 1e-8f);
    for (int ff = 0; ff < 49; ++ff) {
      int f = c * 49 + ff;
      float rv = rnd[f * 512 + j] * inv1;
      float w1 = rv * i1; B1[f * 512 + j] = w1; b1 = fmaf(m1, w1, b1);
      float w2 = rv * i2; B2[f * 512 + j] = w2; b2 = fmaf(m2, w2, b2);
    }
  }
  for (int f = 147; f < 160; ++f) { B1[f * 512 + j] = 0.f; B2[f * 512 + j] = 0.f; }
  bias[j] = b1; bias[512 + j] = b2;
}

// C[n][m] col-major (stride 16384) = A[M][160] * B[160][512] - bias[n]
#define GBM 128
#define GBN 128
#define GBK 16
__global__ __launch_bounds__(256) void gemm_kernel(
    const float* __restrict__ A, const float* __restrict__ B,
    const float* __restrict__ bias, float* __restrict__ C, int M) {
  __shared__ __align__(16) float As[GBK][GBM + 4];
  __shared__ __align__(16) float Bs[GBK][GBN];
  int bm = blockIdx.x * GBM;
  int bn = blockIdx.y * GBN;
  int tid = threadIdx.x;
  int tm = tid & 15;
  int tn = tid >> 4;
  float acc[8][8] = {{0.f}};
  for (int k0 = 0; k0 < 160; k0 += GBK) {
#pragma unroll
    for (int i = 0; i < 2; ++i) {
      int q = tid + i * 256;
      int r = q >> 2, c4 = (q & 3) << 2;
      float4 va = *(const float4*)(A + (size_t)(bm + r) * 160 + k0 + c4);
      As[c4 + 0][r] = va.x; As[c4 + 1][r] = va.y;
      As[c4 + 2][r] = va.z; As[c4 + 3][r] = va.w;
    }
#pragma unroll
    for (int i = 0; i < 2; ++i) {
      int q = tid + i * 256;
      int r = q >> 5, c = (q & 31) << 2;
      *(float4*)(&Bs[r][c]) = *(const float4*)(B + (size_t)(k0 + r) * 512 + bn + c);
    }
    __syncthreads();
#pragma unroll
    for (int kk = 0; kk < GBK; ++kk) {
      float4 a0 = *(const float4*)(&As[kk][tm * 8]);
      float4 a1 = *(const float4*)(&As[kk][tm * 8 + 4]);
      float4 b0 = *(const float4*)(&Bs[kk][tn * 8]);
      float4 b1 = *(const float4*)(&Bs[kk][tn * 8 + 4]);
      float av[8] = {a0.x, a0.y, a0.z, a0.w, a1.x, a1.y, a1.z, a1.w};
      float bv[8] = {b0.x, b0.y, b0.z, b0.w, b1.x, b1.y, b1.z, b1.w};
#pragma unroll
      for (int i = 0; i < 8; ++i)
#pragma unroll
        for (int jj = 0; jj < 8; ++jj)
          acc[i][jj] = fmaf(av[i], bv[jj], acc[i][jj]);
    }
    __syncthreads();
  }
#pragma unroll
  for (int jj = 0; jj < 8; ++jj) {
    int n = bn + tn * 8 + jj;
    float bb = bias[n];
    float4 v0 = make_float4(acc[0][jj] - bb, acc[1][jj] - bb, acc[2][jj] - bb, acc[3][jj] - bb);
    float4 v1 = make_float4(acc[4][jj] - bb, acc[5][jj] - bb, acc[6][jj] - bb, acc[7][jj] - bb);
    float* cp = C + (size_t)n * 16384 + bm + tm * 8;
    *(float4*)cp = v0;
    *(float4*)(cp + 4) = v1;
  }
}

// ---- hybrid sort + diff ----
// co-rank: smallest i in [max(0,so-L), min(so,L)] s.t. merged prefix of size
// so takes i from A, so-i from B. Convention: advance while A[i] < B[so-1-i].
__device__ inline int corank(const float* __restrict__ s, int pb, int L, int so) {
  int lo = so - L; lo = lo < 0 ? 0 : lo;
  int hi = so < L ? so : L;
  while (lo < hi) {
    int mid = (lo + hi) >> 1;
    float a = s[pb + mid];
    float b = s[pb + L + so - 1 - mid];
    if (a < b) lo = mid + 1; else hi = mid;
  }
  return lo;
}

__global__ __launch_bounds__(1024) void sortdiff_kernel(
    float* __restrict__ proj1, const float* __restrict__ proj2,
    float* __restrict__ sum, int m) {
  __shared__ float s[16384];
  int t = threadIdx.x;
  int col = blockIdx.x;  // 0..511
  const float INF = __builtin_huge_valf();
  float v[16];
  int bi = t << 4;
  float acc = 0.f;

  for (int phase = 0; phase < 2; ++phase) {
    float* basep = (phase ? (float*)proj2 : proj1) + (size_t)col * 16384;
    if (bi < m) {
#pragma unroll
      for (int i = 0; i < 4; ++i) {
        float4 L4 = *(const float4*)(basep + bi + i * 4);
        v[i * 4 + 0] = L4.x; v[i * 4 + 1] = L4.y;
        v[i * 4 + 2] = L4.z; v[i * 4 + 3] = L4.w;
      }
    } else {
#pragma unroll
      for (int r = 0; r < 16; ++r) v[r] = INF;
    }

    // ---- in-thread bitonic, k=2..8 (direction from r bits, compile-time)
#pragma unroll
    for (int k = 2; k <= 8; k <<= 1) {
#pragma unroll
      for (int j = k >> 1; j >= 1; j >>= 1) {
#pragma unroll
        for (int r = 0; r < 16; ++r) {
          if ((r & j) == 0) {
            bool up = ((r & k) == 0);
            float a = v[r], b = v[r | j];
            float lo = fminf(a, b), hi = fmaxf(a, b);
            v[r] = up ? lo : hi;
            v[r | j] = up ? hi : lo;
          }
        }
      }
    }
    // ---- wave-level bitonic, k=16..1024 (k=1024 forced ascending)
    for (int k = 16; k <= 1024; k <<= 1) {
      bool upk = (k == 1024) || ((bi & k) == 0);
      for (int j = k >> 1; j >= 16; j >>= 1) {
        int d = j >> 4;  // lanes 1..32
        bool keepmin = (upk == ((t & d) == 0));
#pragma unroll
        for (int r = 0; r < 16; ++r) {
          float pv = __shfl_xor(v[r], d, 64);
          float lo = fminf(v[r], pv), hi = fmaxf(v[r], pv);
          v[r] = keepmin ? lo : hi;
        }
      }
#pragma unroll
      for (int j = 8; j >= 1; j >>= 1) {
#pragma unroll
        for (int r = 0; r < 16; ++r) {
          if ((r & j) == 0) {
            float a = v[r], b = v[r | j];
            float lo = fminf(a, b), hi = fmaxf(a, b);
            v[r] = upk ? lo : hi;
            v[r | j] = upk ? hi : lo;
          }
        }
      }
    }

    // each wave's 1024 elements now sorted ascending; stage to LDS
    __syncthreads();
#pragma unroll
    for (int i = 0; i < 4; ++i)
      *(float4*)(&s[bi + i * 4]) =
          make_float4(v[i * 4], v[i * 4 + 1], v[i * 4 + 2], v[i * 4 + 3]);
    __syncthreads();

    // ---- 4 merge-path rounds: L = 1024, 2048, 4096, 8192
    for (int L = 1024; L <= 8192; L <<= 1) {
      int pb = bi & ~(2 * L - 1);
      int so = bi - pb;
      int i0 = corank(s, pb, L, so);
      int i1 = corank(s, pb, L, so + 16);
      int na = i1 - i0;
      int j1 = so + 16 - i1;
#pragma unroll
      for (int q = 0; q < 16; ++q) {
        int idx = (q < na) ? (pb + i0 + q)
                           : (pb + L + j1 - 1 - (q - na));
        v[q] = s[idx];
      }
      // window = ascending A-part then descending B-part => bitonic; merge up
#pragma unroll
      for (int j = 8; j >= 1; j >>= 1) {
#pragma unroll
        for (int q = 0; q < 16; ++q) {
          if ((q & j) == 0) {
            float a = v[q], b = v[q | j];
            v[q] = fminf(a, b);
            v[q | j] = fmaxf(a, b);
          }
        }
      }
      __syncthreads();
      if (L < 8192) {
#pragma unroll
        for (int i = 0; i < 4; ++i)
          *(float4*)(&s[bi + i * 4]) =
              make_float4(v[i * 4], v[i * 4 + 1], v[i * 4 + 2], v[i * 4 + 3]);
        __syncthreads();
      }
    }

    if (phase == 0) {
      // write sorted column back to global (own positions; re-read in phase 1)
#pragma unroll
      for (int i = 0; i < 4; ++i)
        *(float4*)(basep + bi + i * 4) =
            make_float4(v[i * 4], v[i * 4 + 1], v[i * 4 + 2], v[i * 4 + 3]);
    } else if (bi < m) {
      const float* s1 = proj1 + (size_t)col * 16384;
#pragma unroll
      for (int i = 0; i < 4; ++i) {
        float4 a = *(const float4*)(s1 + bi + i * 4);
        acc += fabsf(a.x - v[i * 4 + 0]);
        acc += fabsf(a.y - v[i * 4 + 1]);
        acc += fabsf(a.z - v[i * 4 + 2]);
        acc += fabsf(a.w - v[i * 4 + 3]);
      }
    }
  }

#pragma unroll
  for (int o = 32; o > 0; o >>= 1) acc += __shfl_down(acc, o, 64);
  __syncthreads();
  if ((t & 63) == 0) s[t >> 6] = acc;
  __syncthreads();
  if (t == 0) {
    float tot = 0.f;
    for (int i = 0; i < 16; ++i) tot += s[i];
    atomicAdd(sum, tot);
  }
}

__global__ void final_kernel(const float* __restrict__ sums, float* __restrict__ out) {
  float r = sums[0] * (1.f / 8388608.f) + sums[1] * (1.f / 8388608.f) +
            sums[2] * (1.f / 8388608.f) + sums[3] * (1.f / 8388608.f) +
            sums[4] * (1.f / 6553600.f);
  out[0] = r * (1000.f / 5.f);
}

// ---------------------------------------------------------------------------

extern "C" void kernel_launch(void* const* d_in, const int* in_sizes, int n_in,
                              void* d_out, int out_size, void* d_ws, size_t ws_size,
                              hipStream_t stream) {
  const float* xin = (const float*)d_in[0];
  const float* yin = (const float*)d_in[1];
  float* out = (float*)d_out;

  char* base = (char*)d_ws;
  size_t off = 0;
  auto alloc = [&](size_t nfloats) -> float* {
    float* p = (float*)(base + off);
    off += ((nfloats * 4) + 255) & ~(size_t)255;
    return p;
  };
  float* gX[5];
  float* gY[5];
  gX[0] = (float*)xin;
  gY[0] = (float*)yin;
  gX[1] = alloc(6291456); gX[2] = alloc(1572864); gX[3] = alloc(393216); gX[4] = alloc(98304);
  gY[1] = alloc(6291456); gY[2] = alloc(1572864); gY[3] = alloc(393216); gY[4] = alloc(98304);
  float* p1 = alloc((size_t)16384 * 160);
  float* p2 = alloc((size_t)16384 * 160);
  float* rnd = alloc(160 * 512);
  float* B1 = alloc(160 * 512);
  float* B2 = alloc(160 * 512);
  float* biasb = alloc(1024);
  float* proj1 = alloc((size_t)16384 * 512);
  float* proj2 = alloc((size_t)16384 * 512);
  float* misc = alloc(128);

  static const int Hs[5] = {256, 128, 64, 32, 16};

  init_kernel<<<1, 128, 0, stream>>>(misc);
  for (int t = 0; t < 2; ++t) {
    const float* in0 = t ? yin : xin;
    float** g = t ? gY : gX;
    down_kernel<<<(384 * 128 * 128 + 255) / 256, 256, 0, stream>>>(in0, g[1], 256, 256, 384 * 128 * 128);
    down_kernel<<<(384 * 64 * 64 + 255) / 256, 256, 0, stream>>>(g[1], g[2], 128, 128, 384 * 64 * 64);
    down_kernel<<<(384 * 32 * 32 + 255) / 256, 256, 0, stream>>>(g[2], g[3], 64, 64, 384 * 32 * 32);
    down_kernel<<<(384 * 16 * 16 + 255) / 256, 256, 0, stream>>>(g[3], g[4], 32, 32, 384 * 16 * 16);
  }
  for (int l = 0; l < 5; ++l) {
    int H = Hs[l];
    int Wm6 = H - 6;
    int n = Wm6 * Wm6;
    int nd = n < 128 ? n : 128;
    int M = 128 * nd;
    randgen_kernel<<<320, 256, 0, stream>>>(rnd, g_tbl.kp0[l], g_tbl.kp1[l]);
    int totalE = M * 160;
    float* st1 = misc + 8 + l * 16;
    float* st2 = st1 + 6;
    extract_kernel<<<(totalE + 255) / 256, 256, 0, stream>>>(
        gX[l], (l < 4) ? gX[l + 1] : nullptr, p1, st1, g_tbl.rcs[l], H, nd, (l < 4) ? 1 : 0, totalE);
    extract_kernel<<<(totalE + 255) / 256, 256, 0, stream>>>(
        gY[l], (l < 4) ? gY[l + 1] : nullptr, p2, st2, g_tbl.rcs[l], H, nd, (l < 4) ? 1 : 0, totalE);
    prep_kernel<<<2, 256, 0, stream>>>(rnd, st1, B1, B2, biasb, (float)M * 49.f);
    dim3 gg(M / 128, 4);
    gemm_kernel<<<gg, 256, 0, stream>>>(p1, B1, biasb, proj1, M);
    gemm_kernel<<<gg, 256, 0, stream>>>(p2, B2, biasb + 512, proj2, M);
    sortdiff_kernel<<<512, 1024, 0, stream>>>(proj1, proj2, misc + l, M);
  }
  final_kernel<<<1, 1, 0, stream>>>(misc, out);
}